// Round 17
// baseline (222.158 us; speedup 1.0000x reference)
//
#include <hip/hip_runtime.h>
#include <stdint.h>
#include <math.h>

#define NANCH 261888
#define NBATCH 16
#define PRE_NMS 12000
#define POST_NMS 2000
#define NBINS 21845        // sum of 8 grids: 128^2+64^2+...+1
#define BINCAP 98304       // per-batch bin-list entry capacity (< 2^17)
#define NCHUNK 188         // ceil(12000/64)
#define VBINS 4096         // value-select buckets
#define CANDCAP 16384      // boundary-bucket candidate capacity per batch
#define ADJR 12            // fixed adjacency slots per box (6 u32 words)
#define OVFCAP 4096        // per-batch overflow pair capacity
#define GPRELOAD 4096      // ranks preloaded into LDS in k_greedy

// ---------- key construction: (ordered score bits << 32) | ~index ----------
__device__ __forceinline__ uint64_t make_key(float s, int i) {
    uint32_t u = __float_as_uint(s);
    u ^= (u >> 31) ? 0xFFFFFFFFu : 0x80000000u;   // total order for floats
    return ((uint64_t)u << 32) | (uint32_t)(~(uint32_t)i);
}

// exact kill test: div_rn(inter,denom) > 0.7f (proven exact, absmax=0 r2-r16);
// symmetric in (a,c).
__device__ __forceinline__ bool kill_pair(float4 a, float4 c) {
    const double MD = (double)0.7f + 2.9802322387695312e-08;   // 0.7f + 2^-25
    float xx1 = fmaxf(a.x, c.x), yy1 = fmaxf(a.y, c.y);
    float xx2 = fminf(a.z, c.z), yy2 = fminf(a.w, c.w);
    float ww = fmaxf(__fadd_rn(__fsub_rn(xx2, xx1), 1.0f), 0.0f);
    float hh = fmaxf(__fadd_rn(__fsub_rn(yy2, yy1), 1.0f), 0.0f);
    float inter = __fmul_rn(ww, hh);
    float aa = __fmul_rn(__fadd_rn(__fsub_rn(a.z, a.x), 1.0f),
                         __fadd_rn(__fsub_rn(a.w, a.y), 1.0f));
    float ab = __fmul_rn(__fadd_rn(__fsub_rn(c.z, c.x), 1.0f),
                         __fadd_rn(__fsub_rn(c.w, c.y), 1.0f));
    float denom = __fsub_rn(__fadd_rn(aa, ab), inter);
    return !((double)inter < MD * (double)denom);
}

// monotone value bucket for top-k select (MUST be identical in histv/splitv)
__device__ __forceinline__ int vbucket(float s) {
    int bk = (int)(s * 4096.0f);
    return min(max(bk, 0), VBINS - 1);
}

// ---------- init: zero hist + counters (deg zeroed in k_rankb epilogue) ------
__global__ void k_init(uint32_t* hist, uint32_t* cnt, uint32_t* ccnt,
                       uint32_t* ovfc, uint32_t* segcur) {
    int tid = blockIdx.x * 256 + threadIdx.x;
    int stride = gridDim.x * 256;
    for (int i = tid; i < NBATCH * VBINS; i += stride) hist[i] = 0;
    if (tid < NBATCH) { cnt[tid] = 0; ccnt[tid] = 0; ovfc[tid] = 0; segcur[tid] = 0; }
}

// ---------- value histogram over scores (4096 buckets per batch) ----------
__global__ __launch_bounds__(256) void k_histv(const float* __restrict__ scores,
                                               uint32_t* __restrict__ hist) {
    __shared__ uint32_t lh[VBINS];
    int tid = threadIdx.x;
    int b = blockIdx.y;
    for (int i = tid; i < VBINS; i += 256) lh[i] = 0;
    __syncthreads();
    const float* sc = scores + (size_t)b * NANCH;
    for (int i = blockIdx.x * 256 + tid; i < NANCH; i += gridDim.x * 256)
        atomicAdd(&lh[vbucket(sc[i])], 1u);
    __syncthreads();
    for (int i = tid; i < VBINS; i += 256) {
        uint32_t c = lh[i];
        if (c) atomicAdd(&hist[b * VBINS + i], c);
    }
}

// ---------- pick threshold bucket B (1 wave per batch) ----------
__global__ __launch_bounds__(64) void k_pickv(const uint32_t* __restrict__ hist,
                                              uint32_t* __restrict__ Bsel) {
    int b = blockIdx.x;
    int ln = threadIdx.x;
    const uint32_t* h = hist + b * VBINS;
    int hi = VBINS - 1 - 64 * ln;     // my chunk: bins [hi-63, hi], descending
    uint32_t tot = 0;
    for (int k = 0; k < 64; ++k) tot += h[hi - k];
    uint32_t x = tot;
    for (int d = 1; d < 64; d <<= 1) { uint32_t y = __shfl_up(x, d); if (ln >= d) x += y; }
    uint32_t excl = x - tot;          // count in buckets above my chunk
    bool hitc = (excl < (uint32_t)PRE_NMS) && (excl + tot >= (uint32_t)PRE_NMS);
    unsigned long long bal = __ballot(hitc);
    int L = __ffsll(bal) - 1;
    if (ln == L) {
        uint32_t cum = excl;
        for (int k = 0; k < 64; ++k) {
            int bin = hi - k;
            uint32_t c = h[bin];
            if (cum + c >= (uint32_t)PRE_NMS) { Bsel[b] = (uint32_t)bin; break; }
            cum += c;
        }
    }
}

// ---------- split: block-aggregated compaction (1 global atomic per side) ----
__global__ __launch_bounds__(256) void k_splitv(const float* __restrict__ scores,
                                                const uint32_t* __restrict__ Bsel,
                                                uint32_t* __restrict__ cnt,
                                                uint32_t* __restrict__ ccnt,
                                                uint64_t* __restrict__ selk,
                                                uint64_t* __restrict__ candbuf) {
    __shared__ uint64_t lbuf[2048];
    __shared__ uint32_t lcnt, lccnt, lbase, lcbase;
    int tid = threadIdx.x;
    int b = blockIdx.y;
    int ln = tid & 63;
    if (tid == 0) { lcnt = 0; lccnt = 0; }
    __syncthreads();
    uint32_t B = Bsel[b];
    const float* sc = scores + (size_t)b * NANCH;
    int base0 = blockIdx.x * 2048;
    for (int r = 0; r < 8; ++r) {
        int i = base0 + r * 256 + tid;
        bool psel = false, pcand = false;
        uint64_t key = 0;
        if (i < NANCH) {
            float s = sc[i];
            int bk = vbucket(s);
            psel = ((uint32_t)bk > B);
            pcand = ((uint32_t)bk == B);
            if (psel || pcand) key = make_key(s, i);
        }
        unsigned long long bs = __ballot(psel);
        uint32_t wb = 0;
        if (ln == 0 && bs) wb = atomicAdd(&lcnt, (uint32_t)__popcll(bs));
        wb = __shfl(wb, 0);
        if (psel) lbuf[wb + (uint32_t)__popcll(bs & ((1ull << ln) - 1ull))] = key;
        unsigned long long bcm = __ballot(pcand);
        uint32_t wc = 0;
        if (ln == 0 && bcm) wc = atomicAdd(&lccnt, (uint32_t)__popcll(bcm));
        wc = __shfl(wc, 0);
        if (pcand) lbuf[2047 - (wc + (uint32_t)__popcll(bcm & ((1ull << ln) - 1ull)))] = key;
    }
    __syncthreads();
    if (tid == 0) {
        lbase = lcnt ? atomicAdd(&cnt[b], lcnt) : 0u;
        lcbase = lccnt ? atomicAdd(&ccnt[b], lccnt) : 0u;
    }
    __syncthreads();
    uint32_t n = lcnt, bsx = lbase;
    for (uint32_t i = tid; i < n; i += 256)
        selk[(size_t)b * PRE_NMS + bsx + i] = lbuf[i];
    uint32_t nc = lccnt, bcx = lcbase;
    for (uint32_t i = tid; i < nc; i += 256) {
        uint32_t p = bcx + i;
        if (p < CANDCAP) candbuf[(size_t)b * CANDCAP + p] = lbuf[2047 - i];
    }
}

// ---------- bucket rank + FUSED gather/decode/clip + deg zero ----------
// Computes exact descending rank for all 12000 keys (adaptive value buckets +
// exact in-bucket compares), then directly decodes each key's anchor box into
// props[b][rank] (identical __f*_rn arithmetic; exp via double). aidx buffer
// eliminated. Epilogue zeroes deg for k_search.
__global__ __launch_bounds__(1024) void k_rankb(const uint64_t* __restrict__ selk,
                                                const uint64_t* __restrict__ candbuf,
                                                const uint32_t* __restrict__ cnt,
                                                const uint32_t* __restrict__ ccnt,
                                                const float4* __restrict__ anchors,
                                                const float4* __restrict__ deltas,
                                                const float* __restrict__ im_info,
                                                float4* __restrict__ props,
                                                uint32_t* __restrict__ deg) {
    __shared__ uint64_t kys[PRE_NMS];        // 96000 B
    __shared__ uint32_t bbase[2048];
    __shared__ uint32_t bcur[2048];
    __shared__ uint16_t blist[PRE_NMS];
    __shared__ float redf[32];
    __shared__ uint32_t wsum[16];
    __shared__ uint32_t appcnt;
    int b = blockIdx.x, t = threadIdx.x, wv = t >> 6, ln = t & 63;
    const uint64_t* sk = selk + (size_t)b * PRE_NMS;
    const uint64_t* cb = candbuf + (size_t)b * CANDCAP;
    int nc = (int)cnt[b];
    int m = (int)min(ccnt[b], (uint32_t)CANDCAP);
    uint32_t nd = (uint32_t)(PRE_NMS - nc);
    if (t == 0) appcnt = 0;
    for (int i = t; i < 2048; i += 1024) bcur[i] = 0;
    float lmin = 1e30f, lmax = -1e30f;
    for (int i = t; i < nc; i += 1024) {
        uint64_t k = sk[i];
        kys[i] = k;
        float s = __uint_as_float((uint32_t)(k >> 32) ^ 0x80000000u);
        lmin = fminf(lmin, s); lmax = fmaxf(lmax, s);
    }
    __syncthreads();                          // appcnt=0 visible
    // boundary candidates: exact rank among candidates; append top nd
    for (int i = t; i < m; i += 1024) {
        uint64_t ki = cb[i];
        int rk = 0;
        for (int j = 0; j < m; ++j) rk += (cb[j] > ki) ? 1 : 0;
        if ((uint32_t)rk < nd) {
            uint32_t pos = (uint32_t)nc + atomicAdd(&appcnt, 1u);
            kys[pos] = ki;
            float s = __uint_as_float((uint32_t)(ki >> 32) ^ 0x80000000u);
            lmin = fminf(lmin, s); lmax = fmaxf(lmax, s);
        }
    }
    for (int d = 1; d < 64; d <<= 1) {
        lmin = fminf(lmin, __shfl_xor(lmin, d));
        lmax = fmaxf(lmax, __shfl_xor(lmax, d));
    }
    if (ln == 0) { redf[wv] = lmin; redf[16 + wv] = lmax; }
    __syncthreads();                          // kys complete; redf ready
    float smin = redf[0], smax = redf[16];
    for (int w = 1; w < 16; ++w) { smin = fminf(smin, redf[w]); smax = fmaxf(smax, redf[16 + w]); }
    float scale = 2047.0f / fmaxf(smax - smin, 1e-20f);
    for (int i = t; i < PRE_NMS; i += 1024) {
        float s = __uint_as_float((uint32_t)(kys[i] >> 32) ^ 0x80000000u);
        int bk = min(max((int)((s - smin) * scale), 0), 2047);
        atomicAdd(&bcur[bk], 1u);
    }
    __syncthreads();
    {
        int r0 = 2 * t;
        uint32_t a0 = bcur[2047 - r0];
        uint32_t a1 = bcur[2046 - r0];
        uint32_t tot = a0 + a1;
        uint32_t x = tot;
        for (int d = 1; d < 64; d <<= 1) { uint32_t y = __shfl_up(x, d); if (ln >= d) x += y; }
        if (ln == 63) wsum[wv] = x;
        __syncthreads();
        uint32_t wb = 0;
        for (int w = 0; w < 16; ++w) wb += (w < wv) ? wsum[w] : 0u;
        uint32_t excl = wb + x - tot;
        bbase[2047 - r0] = excl;
        bbase[2046 - r0] = excl + a0;
        bcur[2047 - r0] = excl;
        bcur[2046 - r0] = excl + a0;
    }
    __syncthreads();
    for (int i = t; i < PRE_NMS; i += 1024) {
        float s = __uint_as_float((uint32_t)(kys[i] >> 32) ^ 0x80000000u);
        int bk = min(max((int)((s - smin) * scale), 0), 2047);
        uint32_t pos = atomicAdd(&bcur[bk], 1u);
        blist[pos] = (uint16_t)i;
    }
    __syncthreads();
    float xmax = __fsub_rn(im_info[b * 3 + 1], 1.0f);
    float ymax = __fsub_rn(im_info[b * 3 + 0], 1.0f);
    for (int i = t; i < PRE_NMS; i += 1024) {
        uint64_t ki = kys[i];
        float s = __uint_as_float((uint32_t)(ki >> 32) ^ 0x80000000u);
        int bk = min(max((int)((s - smin) * scale), 0), 2047);
        uint32_t start = bbase[bk], end = bcur[bk];
        int rk = 0;
        for (uint32_t p = start; p < end; ++p) {
            int j = (int)blist[p];
            rk += (kys[j] > ki) ? 1 : 0;
        }
        uint32_t pos = bbase[bk] + (uint32_t)rk;
        uint32_t a = ~(uint32_t)(ki & 0xFFFFFFFFull);
        float4 an = anchors[a];
        float4 dl = deltas[(size_t)b * NANCH + a];
        float w  = __fadd_rn(__fsub_rn(an.z, an.x), 1.0f);
        float h  = __fadd_rn(__fsub_rn(an.w, an.y), 1.0f);
        float cx = __fadd_rn(an.x, __fmul_rn(0.5f, w));
        float cy = __fadd_rn(an.y, __fmul_rn(0.5f, h));
        float pcx = __fadd_rn(__fmul_rn(dl.x, w), cx);
        float pcy = __fadd_rn(__fmul_rn(dl.y, h), cy);
        float ew = (float)exp((double)dl.z);
        float eh = (float)exp((double)dl.w);
        float pw = __fmul_rn(ew, w);
        float ph = __fmul_rn(eh, h);
        float x1 = __fsub_rn(pcx, __fmul_rn(0.5f, pw));
        float y1 = __fsub_rn(pcy, __fmul_rn(0.5f, ph));
        float x2 = __fadd_rn(pcx, __fmul_rn(0.5f, pw));
        float y2 = __fadd_rn(pcy, __fmul_rn(0.5f, ph));
        x1 = fminf(fmaxf(x1, 0.0f), xmax);
        y1 = fminf(fmaxf(y1, 0.0f), ymax);
        x2 = fminf(fmaxf(x2, 0.0f), xmax);
        y2 = fminf(fmaxf(y2, 0.0f), ymax);
        props[(size_t)b * PRE_NMS + pos] = make_float4(x1, y1, x2, y2);
    }
    // zero deg for k_search (replaces k_init's pass)
    for (int i = t; i < PRE_NMS; i += 1024) deg[(size_t)b * PRE_NMS + i] = 0u;
}

// ---------- spatial binning helpers ----------
__device__ __forceinline__ int bucket_of(float w) {
    int iw = (int)w;                 // w >= 1
    int bb = 31 - __clz(iw);
    return min(max(bb, 2), 9);
}
__device__ __forceinline__ int grid_base(int g) {        // bins before grid g
    return (65536 - (65536 >> ((g - 2) * 2))) / 3;
}

// ---------- binning, 8-way grid-parallel + packed bin descriptor (r15) ------
__global__ __launch_bounds__(1024) void k_binfuse8(const float4* __restrict__ props,
                                                   uint32_t* __restrict__ binpack,
                                                   uint16_t* __restrict__ binlist,
                                                   uint32_t* __restrict__ segcur) {
    __shared__ uint32_t bc[16384];            // 64 KB (g=2 worst case)
    __shared__ uint32_t wsum[16];
    __shared__ uint32_t stot, sbase;
    int b = blockIdx.x;
    int g = 2 + blockIdx.y;
    int t = threadIdx.x, wv = t >> 6, ln = t & 63;
    int cs = g + 1, dim = 128 >> (g - 2);
    int dim2 = dim * dim;
    int gb = grid_base(g);
    for (int i = t; i < dim2; i += 1024) bc[i] = 0;
    __syncthreads();
    const float4* pb = props + (size_t)b * PRE_NMS;
    // count
    for (int i = t; i < PRE_NMS; i += 1024) {
        float4 p = pb[i];
        float w = __fadd_rn(__fsub_rn(p.z, p.x), 1.0f);
        if (bucket_of(w) != g) continue;
        int cx0 = ((int)p.x) >> cs, cx1 = ((int)p.z) >> cs;
        int cy0 = ((int)p.y) >> cs, cy1 = ((int)p.w) >> cs;
        for (int cy = cy0; cy <= cy1; ++cy)
            for (int cx = cx0; cx <= cx1; ++cx)
                atomicAdd(&bc[cy * dim + cx], 1u);
    }
    __syncthreads();
    // local exclusive scan over dim2 bins
    int per = (dim2 + 1023) >> 10;
    int i0 = t * per, i1 = min(i0 + per, dim2);
    uint32_t tot = 0;
    for (int k = i0; k < i1; ++k) tot += bc[k];
    uint32_t x = tot;
    for (int d = 1; d < 64; d <<= 1) { uint32_t y = __shfl_up(x, d); if (ln >= d) x += y; }
    if (ln == 63) wsum[wv] = x;
    __syncthreads();
    uint32_t wb = 0;
    for (int w2 = 0; w2 < 16; ++w2) wb += (w2 < wv) ? wsum[w2] : 0u;
    uint32_t excl = wb + x - tot;
    if (t == 1023) stot = excl + tot;
    __syncthreads();
    if (t == 0) sbase = atomicAdd(&segcur[b], stot);
    __syncthreads();
    uint32_t base = sbase;
    uint32_t* pkb = binpack + (size_t)b * NBINS;
    uint32_t run = base + excl;
    for (int k = i0; k < i1; ++k) {
        uint32_t c = bc[k];
        pkb[gb + k] = run | (c << 17);
        bc[k] = run;
        run += c;
    }
    __syncthreads();
    // fill
    uint16_t* bl = binlist + (size_t)b * BINCAP;
    for (int i = t; i < PRE_NMS; i += 1024) {
        float4 p = pb[i];
        float w = __fadd_rn(__fsub_rn(p.z, p.x), 1.0f);
        if (bucket_of(w) != g) continue;
        int cx0 = ((int)p.x) >> cs, cx1 = ((int)p.z) >> cs;
        int cy0 = ((int)p.y) >> cs, cy1 = ((int)p.w) >> cs;
        for (int cy = cy0; cy <= cy1; ++cy)
            for (int cx = cx0; cx <= cx1; ++cx) {
                uint32_t pos = atomicAdd(&bc[cy * dim + cx], 1u);
                uint32_t e = (uint32_t)i | ((cx == cx0) ? 0x4000u : 0u)
                                        | ((cy == cy0) ? 0x8000u : 0u);
                if (pos < BINCAP) bl[pos] = (uint16_t)e;
            }
    }
}

// ---------- single-pass symmetric kill-graph search (r15: 4-way, packed) -----
__global__ __launch_bounds__(256) void k_search(const float4* __restrict__ props,
                                                const uint32_t* __restrict__ binpack,
                                                const uint16_t* __restrict__ binlist,
                                                uint32_t* __restrict__ deg,
                                                uint16_t* __restrict__ adjfix,
                                                uint32_t* __restrict__ ovf,
                                                uint32_t* __restrict__ ovfcnt) {
    int L = blockIdx.x;
    int b = L & (NBATCH - 1);
    int t = threadIdx.x;
    int i = (L >> 4) * 64 + (t >> 2);
    int quar = t & 3;
    if (i >= PRE_NMS) return;
    const float4* pb = props + (size_t)b * PRE_NMS;
    float4 pi = pb[i];
    float wi = __fadd_rn(__fsub_rn(pi.z, pi.x), 1.0f);
    float hi = __fadd_rn(__fsub_rn(pi.w, pi.y), 1.0f);
    int bb = bucket_of(wi);
    const uint32_t* pk = binpack + (size_t)b * NBINS;
    const uint16_t* bl = binlist + (size_t)b * BINCAP;
    uint32_t* degb = deg + (size_t)b * PRE_NMS;
    uint16_t* adjb = adjfix + (size_t)b * PRE_NMS * ADJR;
    uint32_t* ovfb = ovf + (size_t)b * OVFCAP;
    float ex0 = fmaxf(__fsub_rn(pi.x, 1.0f), 0.0f);
    float ey0 = fmaxf(__fsub_rn(pi.y, 1.0f), 0.0f);
    float ex1 = fminf(__fadd_rn(pi.z, 1.0f), 1023.0f);
    float ey1 = fminf(__fadd_rn(pi.w, 1.0f), 1023.0f);

    auto add_edge = [&](int r, int n) {
        uint32_t s = atomicAdd(&degb[r], 1u);
        if (s < ADJR) {
            adjb[(size_t)r * ADJR + s] = (uint16_t)n;
        } else {
            uint32_t p = atomicAdd(&ovfcnt[b], 1u);
            if (p < OVFCAP) ovfb[p] = ((uint32_t)r << 16) | (uint32_t)n;
        }
    };

    #pragma unroll
    for (int pass = 0; pass < 2; ++pass) {
        int g = (pass == 0) ? bb : bb - 1;
        bool tie = (pass == 0);
        if (g < 2) continue;
        int cs = g + 1, dim = 128 >> (g - 2);
        int gb2 = grid_base(g);
        int sx0 = ((int)ex0) >> cs, sx1 = ((int)ex1) >> cs;
        int sy0 = ((int)ey0) >> cs, sy1 = ((int)ey1) >> cs;
        for (int cy = sy0; cy <= sy1; ++cy)
            for (int cx = sx0; cx <= sx1; ++cx) {
                int bin = gb2 + cy * dim + cx;
                uint32_t v = pk[bin];
                uint32_t k0 = v & 0x1FFFFu;
                uint32_t k1 = k0 + (v >> 17);
                for (uint32_t k = k0 + (uint32_t)quar; k < k1; k += 4) {
                    uint32_t ent = bl[k];
                    int j = (int)(ent & 0x3FFFu);
                    if (tie && j <= i) continue;
                    if (!((cx == sx0) || (ent & 0x4000u))) continue;
                    if (!((cy == sy0) || (ent & 0x8000u))) continue;
                    float4 pj = pb[j];
                    float wj = __fadd_rn(__fsub_rn(pj.z, pj.x), 1.0f);
                    float hj = __fadd_rn(__fsub_rn(pj.w, pj.y), 1.0f);
                    if (fminf(wi, wj) < 0.6f * fmaxf(wi, wj)) continue;
                    if (fminf(hi, hj) < 0.6f * fmaxf(hi, hj)) continue;
                    if (kill_pair(pi, pj)) {
                        add_edge(i, j);
                        add_edge(j, i);
                    }
                }
            }
    }
}

// ---------- greedy NMS: 4-wave block, LDS-resident rows (r16) ----------
__global__ __launch_bounds__(256) void k_greedy(const uint32_t* __restrict__ deg,
                                                const uint16_t* __restrict__ adjfix,
                                                const uint32_t* __restrict__ ovf,
                                                const uint32_t* __restrict__ ovfcnt,
                                                const float4* __restrict__ props,
                                                float* __restrict__ out) {
    int b = blockIdx.x;
    int t = threadIdx.x;
    int ln = t & 63;
    __shared__ uint32_t mask[375];                 // 12000 bits
    __shared__ int keeps[POST_NMS];
    __shared__ uint32_t rowl[GPRELOAD * 6];        // 96 KB
    __shared__ uint32_t degl[GPRELOAD];            // 16 KB
    __shared__ int snsel;
    const uint32_t* degb = deg + (size_t)b * PRE_NMS;
    const uint32_t* roww = (const uint32_t*)(adjfix + (size_t)b * PRE_NMS * ADJR);
    const uint32_t* ovfb = ovf + (size_t)b * OVFCAP;
    for (int i = t; i < 375; i += 256) mask[i] = 0xFFFFFFFFu;
    {   // uint4 preload
        const uint4* src = (const uint4*)roww;
        uint4* dst = (uint4*)rowl;
        for (int i = t; i < (GPRELOAD * 6) / 4; i += 256) dst[i] = src[i];
        const uint4* dsrc = (const uint4*)degb;
        uint4* ddst = (uint4*)degl;
        for (int i = t; i < GPRELOAD / 4; i += 256) ddst[i] = dsrc[i];
    }
    __syncthreads();
    if (t < 64) {
        int novf = (int)min(ovfcnt[b], (uint32_t)OVFCAP);
        int nsel = 0;
        for (int c = 0; c < NCHUNK && nsel < POST_NMS; ++c) {
            int r = c * 64 + ln;
            bool inb = (r < PRE_NMS);
            uint32_t dcur = 0;
            uint32_t w[6] = {0, 0, 0, 0, 0, 0};
            if (inb) {
                if (r < GPRELOAD) {
                    dcur = degl[r];
                    #pragma unroll
                    for (int k = 0; k < 6; ++k) w[k] = rowl[r * 6 + k];
                } else {
                    dcur = degb[r];
                    #pragma unroll
                    for (int k = 0; k < 6; ++k) w[k] = roww[(size_t)r * 6 + k];
                }
            }
            int nfix = inb ? min((int)dcur, ADJR) : 0;
            uint32_t base = (uint32_t)(c * 64);
            uint64_t K = 0;
            #pragma unroll
            for (int k = 0; k < ADJR; ++k) {
                if (k < nfix) {
                    uint32_t e = (w[k >> 1] >> ((k & 1) * 16)) & 0xFFFFu;
                    uint32_t d = e - base;
                    if (d < 64u) K |= (1ull << d);
                }
            }
            if (novf && inb) {
                for (int k = 0; k < novf; ++k) {
                    uint32_t e = ovfb[k];
                    if ((int)(e >> 16) == r) {
                        uint32_t d = (e & 0xFFFFu) - base;
                        if (d < 64u) K |= (1ull << d);
                    }
                }
            }
            int vbit = inb ? (int)((mask[r >> 5] >> (r & 31)) & 1u) : 0;
            uint64_t valid = (uint64_t)__ballot(vbit);
            uint32_t Klo = (uint32_t)K, Khi = (uint32_t)(K >> 32);
            uint64_t todo = valid & (uint64_t)__ballot(K != 0);
            while (todo) {
                int s = __ffsll((unsigned long long)todo) - 1;
                if ((valid >> s) & 1ull) {
                    uint32_t kl = (uint32_t)__builtin_amdgcn_readlane((int)Klo, s);
                    uint32_t kh = (uint32_t)__builtin_amdgcn_readlane((int)Khi, s);
                    valid &= ~(((uint64_t)kh << 32) | (uint64_t)kl);
                }
                todo &= (todo - 1);
                todo &= valid;
            }
            uint64_t acc = valid;
            int cnt2 = __popcll(acc);
            int myacc = (int)((acc >> ln) & 1ull);
            uint64_t ltm = (ln == 0) ? 0ull : (~0ull >> (64 - ln));
            int pos = nsel + __popcll(acc & ltm);
            bool eff = myacc && (pos < POST_NMS);
            if (eff) {
                keeps[pos] = r;
                #pragma unroll
                for (int k = 0; k < ADJR; ++k) {
                    if (k < nfix) {
                        uint32_t e = (w[k >> 1] >> ((k & 1) * 16)) & 0xFFFFu;
                        atomicAnd(&mask[e >> 5], ~(1u << (e & 31)));
                    }
                }
                if (novf) {
                    for (int k = 0; k < novf; ++k) {
                        uint32_t e = ovfb[k];
                        if ((int)(e >> 16) == r) {
                            uint32_t n2 = e & 0xFFFFu;
                            atomicAnd(&mask[n2 >> 5], ~(1u << (n2 & 31)));
                        }
                    }
                }
            }
            nsel += cnt2;
        }
        if (ln == 0) snsel = nsel;
    }
    __syncthreads();
    int n = min(snsel, POST_NMS);
    const float4* pb = props + (size_t)b * PRE_NMS;
    float* outb = out + (size_t)b * POST_NMS * 5;
    for (int r = t; r < POST_NMS; r += 256) {
        float* row = outb + (size_t)r * 5;
        if (r < n) {
            float4 p = pb[keeps[r]];
            row[0] = (float)b; row[1] = p.x; row[2] = p.y; row[3] = p.z; row[4] = p.w;
        } else {
            row[0] = (float)b; row[1] = 0.0f; row[2] = 0.0f; row[3] = 0.0f; row[4] = 0.0f;
        }
    }
}

extern "C" void kernel_launch(void* const* d_in, const int* in_sizes, int n_in,
                              void* d_out, int out_size, void* d_ws, size_t ws_size,
                              hipStream_t stream) {
    const float* scores  = (const float*)d_in[0];
    const float* deltas  = (const float*)d_in[1];
    const float* im_info = (const float*)d_in[2];
    const float* anchors = (const float*)d_in[3];
    float* out = (float*)d_out;

    uint8_t* w = (uint8_t*)d_ws;
    uint32_t* hist     = (uint32_t*)(w);                // 262,144
    uint32_t* cnt      = (uint32_t*)(w + 262144);       // 64
    uint32_t* ccnt     = (uint32_t*)(w + 262208);       // 64
    uint32_t* Bsel     = (uint32_t*)(w + 262272);       // 64
    uint32_t* segcur   = (uint32_t*)(w + 262336);       // 64
    uint32_t* ovfcnt   = (uint32_t*)(w + 262400);       // 64 -> 262,464
    uint64_t* selk     = (uint64_t*)(w + 262464);       // 1,536,000 -> 1,798,464
    uint64_t* candbuf  = (uint64_t*)(w + 1798464);      // 2,097,152 -> 3,895,616
    float*    props    = (float*)(w + 4663616);         // 3,072,000 -> 7,735,616
    uint32_t* binpack  = (uint32_t*)(w + 7735616);      // 1,398,144 -> 9,133,760
    uint16_t* binlist  = (uint16_t*)(w + 9133760);      // 3,145,728 -> 12,279,488
    uint32_t* deg      = (uint32_t*)(w + 12279488);     // 768,000   -> 13,047,488
    uint16_t* adjfix   = (uint16_t*)(w + 13047488);     // 4,608,000 -> 17,655,488
    uint32_t* ovf      = (uint32_t*)(w + 17655488);     // 262,144   -> 17,917,632

    hipLaunchKernelGGL(k_init, dim3(64), dim3(256), 0, stream,
                       hist, cnt, ccnt, ovfcnt, segcur);
    hipLaunchKernelGGL(k_histv, dim3(32, NBATCH), dim3(256), 0, stream, scores, hist);
    hipLaunchKernelGGL(k_pickv, dim3(NBATCH), dim3(64), 0, stream, hist, Bsel);
    hipLaunchKernelGGL(k_splitv, dim3(128, NBATCH), dim3(256), 0, stream,
                       scores, Bsel, cnt, ccnt, selk, candbuf);
    hipLaunchKernelGGL(k_rankb, dim3(NBATCH), dim3(1024), 0, stream,
                       selk, candbuf, cnt, ccnt,
                       (const float4*)anchors, (const float4*)deltas, im_info,
                       (float4*)props, deg);
    hipLaunchKernelGGL(k_binfuse8, dim3(NBATCH, 8), dim3(1024), 0, stream,
                       (const float4*)props, binpack, binlist, segcur);
    hipLaunchKernelGGL(k_search, dim3(188 * NBATCH), dim3(256), 0, stream,
                       (const float4*)props, binpack, binlist,
                       deg, adjfix, ovf, ovfcnt);
    hipLaunchKernelGGL(k_greedy, dim3(NBATCH), dim3(256), 0, stream,
                       deg, adjfix, ovf, ovfcnt, (const float4*)props, out);
}

// Round 18
// 205.626 us; speedup vs baseline: 1.0804x; 1.0804x over previous
//
#include <hip/hip_runtime.h>
#include <stdint.h>
#include <math.h>

#define NANCH 261888
#define NBATCH 16
#define PRE_NMS 12000
#define POST_NMS 2000
#define NBINS 21845        // sum of 8 grids: 128^2+64^2+...+1
#define BINCAP 98304       // per-batch bin-list entry capacity (< 2^17)
#define NCHUNK 188         // ceil(12000/64)
#define VBINS 4096         // value-select buckets
#define CANDCAP 16384      // boundary-bucket candidate capacity per batch
#define ADJR 12            // fixed adjacency slots per box (6 u32 words)
#define OVFCAP 4096        // per-batch overflow pair capacity
#define GPRELOAD 4096      // ranks preloaded into LDS in k_greedy

// ---------- key construction: (ordered score bits << 32) | ~index ----------
__device__ __forceinline__ uint64_t make_key(float s, int i) {
    uint32_t u = __float_as_uint(s);
    u ^= (u >> 31) ? 0xFFFFFFFFu : 0x80000000u;   // total order for floats
    return ((uint64_t)u << 32) | (uint32_t)(~(uint32_t)i);
}

// exact kill test: div_rn(inter,denom) > 0.7f (proven exact, absmax=0 r2-r17);
// symmetric in (a,c).
__device__ __forceinline__ bool kill_pair(float4 a, float4 c) {
    const double MD = (double)0.7f + 2.9802322387695312e-08;   // 0.7f + 2^-25
    float xx1 = fmaxf(a.x, c.x), yy1 = fmaxf(a.y, c.y);
    float xx2 = fminf(a.z, c.z), yy2 = fminf(a.w, c.w);
    float ww = fmaxf(__fadd_rn(__fsub_rn(xx2, xx1), 1.0f), 0.0f);
    float hh = fmaxf(__fadd_rn(__fsub_rn(yy2, yy1), 1.0f), 0.0f);
    float inter = __fmul_rn(ww, hh);
    float aa = __fmul_rn(__fadd_rn(__fsub_rn(a.z, a.x), 1.0f),
                         __fadd_rn(__fsub_rn(a.w, a.y), 1.0f));
    float ab = __fmul_rn(__fadd_rn(__fsub_rn(c.z, c.x), 1.0f),
                         __fadd_rn(__fsub_rn(c.w, c.y), 1.0f));
    float denom = __fsub_rn(__fadd_rn(aa, ab), inter);
    return !((double)inter < MD * (double)denom);
}

// monotone value bucket for top-k select (MUST be identical in histv/splitv)
__device__ __forceinline__ int vbucket(float s) {
    int bk = (int)(s * 4096.0f);
    return min(max(bk, 0), VBINS - 1);
}

// ---------- init: zero hist, deg, counters ----------
__global__ void k_init(uint32_t* hist, uint32_t* cnt, uint32_t* ccnt,
                       uint32_t* ovfc, uint32_t* deg, uint32_t* segcur) {
    int tid = blockIdx.x * 256 + threadIdx.x;
    int stride = gridDim.x * 256;
    for (int i = tid; i < NBATCH * VBINS; i += stride) hist[i] = 0;
    for (int i = tid; i < NBATCH * PRE_NMS; i += stride) deg[i] = 0;
    if (tid < NBATCH) { cnt[tid] = 0; ccnt[tid] = 0; ovfc[tid] = 0; segcur[tid] = 0; }
}

// ---------- value histogram over scores (4096 buckets per batch) ----------
__global__ __launch_bounds__(256) void k_histv(const float* __restrict__ scores,
                                               uint32_t* __restrict__ hist) {
    __shared__ uint32_t lh[VBINS];
    int tid = threadIdx.x;
    int b = blockIdx.y;
    for (int i = tid; i < VBINS; i += 256) lh[i] = 0;
    __syncthreads();
    const float* sc = scores + (size_t)b * NANCH;
    for (int i = blockIdx.x * 256 + tid; i < NANCH; i += gridDim.x * 256)
        atomicAdd(&lh[vbucket(sc[i])], 1u);
    __syncthreads();
    for (int i = tid; i < VBINS; i += 256) {
        uint32_t c = lh[i];
        if (c) atomicAdd(&hist[b * VBINS + i], c);
    }
}

// ---------- pick threshold bucket B (1 wave per batch) ----------
__global__ __launch_bounds__(64) void k_pickv(const uint32_t* __restrict__ hist,
                                              uint32_t* __restrict__ Bsel) {
    int b = blockIdx.x;
    int ln = threadIdx.x;
    const uint32_t* h = hist + b * VBINS;
    int hi = VBINS - 1 - 64 * ln;     // my chunk: bins [hi-63, hi], descending
    uint32_t tot = 0;
    for (int k = 0; k < 64; ++k) tot += h[hi - k];
    uint32_t x = tot;
    for (int d = 1; d < 64; d <<= 1) { uint32_t y = __shfl_up(x, d); if (ln >= d) x += y; }
    uint32_t excl = x - tot;          // count in buckets above my chunk
    bool hitc = (excl < (uint32_t)PRE_NMS) && (excl + tot >= (uint32_t)PRE_NMS);
    unsigned long long bal = __ballot(hitc);
    int L = __ffsll(bal) - 1;
    if (ln == L) {
        uint32_t cum = excl;
        for (int k = 0; k < 64; ++k) {
            int bin = hi - k;
            uint32_t c = h[bin];
            if (cum + c >= (uint32_t)PRE_NMS) { Bsel[b] = (uint32_t)bin; break; }
            cum += c;
        }
    }
}

// ---------- split: block-aggregated compaction (1 global atomic per side) ----
__global__ __launch_bounds__(256) void k_splitv(const float* __restrict__ scores,
                                                const uint32_t* __restrict__ Bsel,
                                                uint32_t* __restrict__ cnt,
                                                uint32_t* __restrict__ ccnt,
                                                uint64_t* __restrict__ selk,
                                                uint64_t* __restrict__ candbuf) {
    __shared__ uint64_t lbuf[2048];
    __shared__ uint32_t lcnt, lccnt, lbase, lcbase;
    int tid = threadIdx.x;
    int b = blockIdx.y;
    int ln = tid & 63;
    if (tid == 0) { lcnt = 0; lccnt = 0; }
    __syncthreads();
    uint32_t B = Bsel[b];
    const float* sc = scores + (size_t)b * NANCH;
    int base0 = blockIdx.x * 2048;
    for (int r = 0; r < 8; ++r) {
        int i = base0 + r * 256 + tid;
        bool psel = false, pcand = false;
        uint64_t key = 0;
        if (i < NANCH) {
            float s = sc[i];
            int bk = vbucket(s);
            psel = ((uint32_t)bk > B);
            pcand = ((uint32_t)bk == B);
            if (psel || pcand) key = make_key(s, i);
        }
        unsigned long long bs = __ballot(psel);
        uint32_t wb = 0;
        if (ln == 0 && bs) wb = atomicAdd(&lcnt, (uint32_t)__popcll(bs));
        wb = __shfl(wb, 0);
        if (psel) lbuf[wb + (uint32_t)__popcll(bs & ((1ull << ln) - 1ull))] = key;
        unsigned long long bcm = __ballot(pcand);
        uint32_t wc = 0;
        if (ln == 0 && bcm) wc = atomicAdd(&lccnt, (uint32_t)__popcll(bcm));
        wc = __shfl(wc, 0);
        if (pcand) lbuf[2047 - (wc + (uint32_t)__popcll(bcm & ((1ull << ln) - 1ull)))] = key;
    }
    __syncthreads();
    if (tid == 0) {
        lbase = lcnt ? atomicAdd(&cnt[b], lcnt) : 0u;
        lcbase = lccnt ? atomicAdd(&ccnt[b], lccnt) : 0u;
    }
    __syncthreads();
    uint32_t n = lcnt, bsx = lbase;
    for (uint32_t i = tid; i < n; i += 256)
        selk[(size_t)b * PRE_NMS + bsx + i] = lbuf[i];
    uint32_t nc = lccnt, bcx = lcbase;
    for (uint32_t i = tid; i < nc; i += 256) {
        uint32_t p = bcx + i;
        if (p < CANDCAP) candbuf[(size_t)b * CANDCAP + p] = lbuf[2047 - i];
    }
}

// ---------- bucket rank (fused boundary finish) ----------
__global__ __launch_bounds__(1024) void k_rankb(const uint64_t* __restrict__ selk,
                                                const uint64_t* __restrict__ candbuf,
                                                const uint32_t* __restrict__ cnt,
                                                const uint32_t* __restrict__ ccnt,
                                                uint32_t* __restrict__ aidx) {
    __shared__ uint64_t kys[PRE_NMS];        // 96000 B
    __shared__ uint32_t bbase[2048];
    __shared__ uint32_t bcur[2048];
    __shared__ uint16_t blist[PRE_NMS];
    __shared__ float redf[32];
    __shared__ uint32_t wsum[16];
    __shared__ uint32_t appcnt;
    int b = blockIdx.x, t = threadIdx.x, wv = t >> 6, ln = t & 63;
    const uint64_t* sk = selk + (size_t)b * PRE_NMS;
    const uint64_t* cb = candbuf + (size_t)b * CANDCAP;
    int nc = (int)cnt[b];
    int m = (int)min(ccnt[b], (uint32_t)CANDCAP);
    uint32_t nd = (uint32_t)(PRE_NMS - nc);
    if (t == 0) appcnt = 0;
    for (int i = t; i < 2048; i += 1024) bcur[i] = 0;
    float lmin = 1e30f, lmax = -1e30f;
    for (int i = t; i < nc; i += 1024) {
        uint64_t k = sk[i];
        kys[i] = k;
        float s = __uint_as_float((uint32_t)(k >> 32) ^ 0x80000000u);
        lmin = fminf(lmin, s); lmax = fmaxf(lmax, s);
    }
    __syncthreads();                          // appcnt=0 visible
    // boundary candidates: exact rank among candidates; append top nd
    for (int i = t; i < m; i += 1024) {
        uint64_t ki = cb[i];
        int rk = 0;
        for (int j = 0; j < m; ++j) rk += (cb[j] > ki) ? 1 : 0;
        if ((uint32_t)rk < nd) {
            uint32_t pos = (uint32_t)nc + atomicAdd(&appcnt, 1u);
            kys[pos] = ki;
            float s = __uint_as_float((uint32_t)(ki >> 32) ^ 0x80000000u);
            lmin = fminf(lmin, s); lmax = fmaxf(lmax, s);
        }
    }
    for (int d = 1; d < 64; d <<= 1) {
        lmin = fminf(lmin, __shfl_xor(lmin, d));
        lmax = fmaxf(lmax, __shfl_xor(lmax, d));
    }
    if (ln == 0) { redf[wv] = lmin; redf[16 + wv] = lmax; }
    __syncthreads();                          // kys complete; redf ready
    float smin = redf[0], smax = redf[16];
    for (int w = 1; w < 16; ++w) { smin = fminf(smin, redf[w]); smax = fmaxf(smax, redf[16 + w]); }
    float scale = 2047.0f / fmaxf(smax - smin, 1e-20f);
    for (int i = t; i < PRE_NMS; i += 1024) {
        float s = __uint_as_float((uint32_t)(kys[i] >> 32) ^ 0x80000000u);
        int bk = min(max((int)((s - smin) * scale), 0), 2047);
        atomicAdd(&bcur[bk], 1u);
    }
    __syncthreads();
    {
        int r0 = 2 * t;
        uint32_t a0 = bcur[2047 - r0];
        uint32_t a1 = bcur[2046 - r0];
        uint32_t tot = a0 + a1;
        uint32_t x = tot;
        for (int d = 1; d < 64; d <<= 1) { uint32_t y = __shfl_up(x, d); if (ln >= d) x += y; }
        if (ln == 63) wsum[wv] = x;
        __syncthreads();
        uint32_t wb = 0;
        for (int w = 0; w < 16; ++w) wb += (w < wv) ? wsum[w] : 0u;
        uint32_t excl = wb + x - tot;
        bbase[2047 - r0] = excl;
        bbase[2046 - r0] = excl + a0;
        bcur[2047 - r0] = excl;
        bcur[2046 - r0] = excl + a0;
    }
    __syncthreads();
    for (int i = t; i < PRE_NMS; i += 1024) {
        float s = __uint_as_float((uint32_t)(kys[i] >> 32) ^ 0x80000000u);
        int bk = min(max((int)((s - smin) * scale), 0), 2047);
        uint32_t pos = atomicAdd(&bcur[bk], 1u);
        blist[pos] = (uint16_t)i;
    }
    __syncthreads();
    for (int i = t; i < PRE_NMS; i += 1024) {
        uint64_t ki = kys[i];
        float s = __uint_as_float((uint32_t)(ki >> 32) ^ 0x80000000u);
        int bk = min(max((int)((s - smin) * scale), 0), 2047);
        uint32_t start = bbase[bk], end = bcur[bk];
        int rk = 0;
        for (uint32_t p = start; p < end; ++p) {
            int j = (int)blist[p];
            rk += (kys[j] > ki) ? 1 : 0;
        }
        aidx[(size_t)b * PRE_NMS + bbase[bk] + (uint32_t)rk] = ~(uint32_t)(ki & 0xFFFFFFFFull);
    }
}

// ---------- gather + bbox decode + clip (rank order) ----------
__global__ void k_gather(const float4* __restrict__ anchors, const float4* __restrict__ deltas,
                         const float* __restrict__ im_info, const uint32_t* __restrict__ aidx,
                         float4* __restrict__ props) {
    int b = blockIdx.y;
    int i = blockIdx.x * 256 + threadIdx.x;
    if (i >= PRE_NMS) return;
    uint32_t a = aidx[(size_t)b * PRE_NMS + i];
    float4 an = anchors[a];
    float4 dl = deltas[(size_t)b * NANCH + a];
    float w  = __fadd_rn(__fsub_rn(an.z, an.x), 1.0f);
    float h  = __fadd_rn(__fsub_rn(an.w, an.y), 1.0f);
    float cx = __fadd_rn(an.x, __fmul_rn(0.5f, w));
    float cy = __fadd_rn(an.y, __fmul_rn(0.5f, h));
    float pcx = __fadd_rn(__fmul_rn(dl.x, w), cx);
    float pcy = __fadd_rn(__fmul_rn(dl.y, h), cy);
    float ew = (float)exp((double)dl.z);
    float eh = (float)exp((double)dl.w);
    float pw = __fmul_rn(ew, w);
    float ph = __fmul_rn(eh, h);
    float x1 = __fsub_rn(pcx, __fmul_rn(0.5f, pw));
    float y1 = __fsub_rn(pcy, __fmul_rn(0.5f, ph));
    float x2 = __fadd_rn(pcx, __fmul_rn(0.5f, pw));
    float y2 = __fadd_rn(pcy, __fmul_rn(0.5f, ph));
    float xmax = __fsub_rn(im_info[b * 3 + 1], 1.0f);
    float ymax = __fsub_rn(im_info[b * 3 + 0], 1.0f);
    x1 = fminf(fmaxf(x1, 0.0f), xmax);
    y1 = fminf(fmaxf(y1, 0.0f), ymax);
    x2 = fminf(fmaxf(x2, 0.0f), xmax);
    y2 = fminf(fmaxf(y2, 0.0f), ymax);
    props[(size_t)b * PRE_NMS + i] = make_float4(x1, y1, x2, y2);
}

// ---------- spatial binning helpers ----------
__device__ __forceinline__ int bucket_of(float w) {
    int iw = (int)w;                 // w >= 1
    int bb = 31 - __clz(iw);
    return min(max(bb, 2), 9);
}
__device__ __forceinline__ int grid_base(int g) {        // bins before grid g
    return (65536 - (65536 >> ((g - 2) * 2))) / 3;
}

// ---------- binning, 8-way grid-parallel + packed bin descriptor (r15) ------
__global__ __launch_bounds__(1024) void k_binfuse8(const float4* __restrict__ props,
                                                   uint32_t* __restrict__ binpack,
                                                   uint16_t* __restrict__ binlist,
                                                   uint32_t* __restrict__ segcur) {
    __shared__ uint32_t bc[16384];            // 64 KB (g=2 worst case)
    __shared__ uint32_t wsum[16];
    __shared__ uint32_t stot, sbase;
    int b = blockIdx.x;
    int g = 2 + blockIdx.y;
    int t = threadIdx.x, wv = t >> 6, ln = t & 63;
    int cs = g + 1, dim = 128 >> (g - 2);
    int dim2 = dim * dim;
    int gb = grid_base(g);
    for (int i = t; i < dim2; i += 1024) bc[i] = 0;
    __syncthreads();
    const float4* pb = props + (size_t)b * PRE_NMS;
    // count
    for (int i = t; i < PRE_NMS; i += 1024) {
        float4 p = pb[i];
        float w = __fadd_rn(__fsub_rn(p.z, p.x), 1.0f);
        if (bucket_of(w) != g) continue;
        int cx0 = ((int)p.x) >> cs, cx1 = ((int)p.z) >> cs;
        int cy0 = ((int)p.y) >> cs, cy1 = ((int)p.w) >> cs;
        for (int cy = cy0; cy <= cy1; ++cy)
            for (int cx = cx0; cx <= cx1; ++cx)
                atomicAdd(&bc[cy * dim + cx], 1u);
    }
    __syncthreads();
    // local exclusive scan over dim2 bins
    int per = (dim2 + 1023) >> 10;
    int i0 = t * per, i1 = min(i0 + per, dim2);
    uint32_t tot = 0;
    for (int k = i0; k < i1; ++k) tot += bc[k];
    uint32_t x = tot;
    for (int d = 1; d < 64; d <<= 1) { uint32_t y = __shfl_up(x, d); if (ln >= d) x += y; }
    if (ln == 63) wsum[wv] = x;
    __syncthreads();
    uint32_t wb = 0;
    for (int w2 = 0; w2 < 16; ++w2) wb += (w2 < wv) ? wsum[w2] : 0u;
    uint32_t excl = wb + x - tot;
    if (t == 1023) stot = excl + tot;
    __syncthreads();
    if (t == 0) sbase = atomicAdd(&segcur[b], stot);
    __syncthreads();
    uint32_t base = sbase;
    uint32_t* pkb = binpack + (size_t)b * NBINS;
    uint32_t run = base + excl;
    for (int k = i0; k < i1; ++k) {
        uint32_t c = bc[k];
        pkb[gb + k] = run | (c << 17);
        bc[k] = run;
        run += c;
    }
    __syncthreads();
    // fill
    uint16_t* bl = binlist + (size_t)b * BINCAP;
    for (int i = t; i < PRE_NMS; i += 1024) {
        float4 p = pb[i];
        float w = __fadd_rn(__fsub_rn(p.z, p.x), 1.0f);
        if (bucket_of(w) != g) continue;
        int cx0 = ((int)p.x) >> cs, cx1 = ((int)p.z) >> cs;
        int cy0 = ((int)p.y) >> cs, cy1 = ((int)p.w) >> cs;
        for (int cy = cy0; cy <= cy1; ++cy)
            for (int cx = cx0; cx <= cx1; ++cx) {
                uint32_t pos = atomicAdd(&bc[cy * dim + cx], 1u);
                uint32_t e = (uint32_t)i | ((cx == cx0) ? 0x4000u : 0u)
                                        | ((cy == cy0) ? 0x8000u : 0u);
                if (pos < BINCAP) bl[pos] = (uint16_t)e;
            }
    }
}

// ---------- single-pass symmetric kill-graph search (r15: 4-way, packed) -----
__global__ __launch_bounds__(256) void k_search(const float4* __restrict__ props,
                                                const uint32_t* __restrict__ binpack,
                                                const uint16_t* __restrict__ binlist,
                                                uint32_t* __restrict__ deg,
                                                uint16_t* __restrict__ adjfix,
                                                uint32_t* __restrict__ ovf,
                                                uint32_t* __restrict__ ovfcnt) {
    int L = blockIdx.x;
    int b = L & (NBATCH - 1);
    int t = threadIdx.x;
    int i = (L >> 4) * 64 + (t >> 2);
    int quar = t & 3;
    if (i >= PRE_NMS) return;
    const float4* pb = props + (size_t)b * PRE_NMS;
    float4 pi = pb[i];
    float wi = __fadd_rn(__fsub_rn(pi.z, pi.x), 1.0f);
    float hi = __fadd_rn(__fsub_rn(pi.w, pi.y), 1.0f);
    int bb = bucket_of(wi);
    const uint32_t* pk = binpack + (size_t)b * NBINS;
    const uint16_t* bl = binlist + (size_t)b * BINCAP;
    uint32_t* degb = deg + (size_t)b * PRE_NMS;
    uint16_t* adjb = adjfix + (size_t)b * PRE_NMS * ADJR;
    uint32_t* ovfb = ovf + (size_t)b * OVFCAP;
    float ex0 = fmaxf(__fsub_rn(pi.x, 1.0f), 0.0f);
    float ey0 = fmaxf(__fsub_rn(pi.y, 1.0f), 0.0f);
    float ex1 = fminf(__fadd_rn(pi.z, 1.0f), 1023.0f);
    float ey1 = fminf(__fadd_rn(pi.w, 1.0f), 1023.0f);

    auto add_edge = [&](int r, int n) {
        uint32_t s = atomicAdd(&degb[r], 1u);
        if (s < ADJR) {
            adjb[(size_t)r * ADJR + s] = (uint16_t)n;
        } else {
            uint32_t p = atomicAdd(&ovfcnt[b], 1u);
            if (p < OVFCAP) ovfb[p] = ((uint32_t)r << 16) | (uint32_t)n;
        }
    };

    #pragma unroll
    for (int pass = 0; pass < 2; ++pass) {
        int g = (pass == 0) ? bb : bb - 1;
        bool tie = (pass == 0);
        if (g < 2) continue;
        int cs = g + 1, dim = 128 >> (g - 2);
        int gb2 = grid_base(g);
        int sx0 = ((int)ex0) >> cs, sx1 = ((int)ex1) >> cs;
        int sy0 = ((int)ey0) >> cs, sy1 = ((int)ey1) >> cs;
        for (int cy = sy0; cy <= sy1; ++cy)
            for (int cx = sx0; cx <= sx1; ++cx) {
                int bin = gb2 + cy * dim + cx;
                uint32_t v = pk[bin];
                uint32_t k0 = v & 0x1FFFFu;
                uint32_t k1 = k0 + (v >> 17);
                for (uint32_t k = k0 + (uint32_t)quar; k < k1; k += 4) {
                    uint32_t ent = bl[k];
                    int j = (int)(ent & 0x3FFFu);
                    if (tie && j <= i) continue;
                    if (!((cx == sx0) || (ent & 0x4000u))) continue;
                    if (!((cy == sy0) || (ent & 0x8000u))) continue;
                    float4 pj = pb[j];
                    float wj = __fadd_rn(__fsub_rn(pj.z, pj.x), 1.0f);
                    float hj = __fadd_rn(__fsub_rn(pj.w, pj.y), 1.0f);
                    if (fminf(wi, wj) < 0.6f * fmaxf(wi, wj)) continue;
                    if (fminf(hi, hj) < 0.6f * fmaxf(hi, hj)) continue;
                    if (kill_pair(pi, pj)) {
                        add_edge(i, j);
                        add_edge(j, i);
                    }
                }
            }
    }
}

// ---------- greedy NMS: 4-wave block, LDS-resident rows (r16) ----------
__global__ __launch_bounds__(256) void k_greedy(const uint32_t* __restrict__ deg,
                                                const uint16_t* __restrict__ adjfix,
                                                const uint32_t* __restrict__ ovf,
                                                const uint32_t* __restrict__ ovfcnt,
                                                const float4* __restrict__ props,
                                                float* __restrict__ out) {
    int b = blockIdx.x;
    int t = threadIdx.x;
    int ln = t & 63;
    __shared__ uint32_t mask[375];                 // 12000 bits
    __shared__ int keeps[POST_NMS];
    __shared__ uint32_t rowl[GPRELOAD * 6];        // 96 KB
    __shared__ uint32_t degl[GPRELOAD];            // 16 KB
    __shared__ int snsel;
    const uint32_t* degb = deg + (size_t)b * PRE_NMS;
    const uint32_t* roww = (const uint32_t*)(adjfix + (size_t)b * PRE_NMS * ADJR);
    const uint32_t* ovfb = ovf + (size_t)b * OVFCAP;
    for (int i = t; i < 375; i += 256) mask[i] = 0xFFFFFFFFu;
    {   // uint4 preload
        const uint4* src = (const uint4*)roww;
        uint4* dst = (uint4*)rowl;
        for (int i = t; i < (GPRELOAD * 6) / 4; i += 256) dst[i] = src[i];
        const uint4* dsrc = (const uint4*)degb;
        uint4* ddst = (uint4*)degl;
        for (int i = t; i < GPRELOAD / 4; i += 256) ddst[i] = dsrc[i];
    }
    __syncthreads();
    if (t < 64) {
        int novf = (int)min(ovfcnt[b], (uint32_t)OVFCAP);
        int nsel = 0;
        for (int c = 0; c < NCHUNK && nsel < POST_NMS; ++c) {
            int r = c * 64 + ln;
            bool inb = (r < PRE_NMS);
            uint32_t dcur = 0;
            uint32_t w[6] = {0, 0, 0, 0, 0, 0};
            if (inb) {
                if (r < GPRELOAD) {
                    dcur = degl[r];
                    #pragma unroll
                    for (int k = 0; k < 6; ++k) w[k] = rowl[r * 6 + k];
                } else {
                    dcur = degb[r];
                    #pragma unroll
                    for (int k = 0; k < 6; ++k) w[k] = roww[(size_t)r * 6 + k];
                }
            }
            int nfix = inb ? min((int)dcur, ADJR) : 0;
            uint32_t base = (uint32_t)(c * 64);
            uint64_t K = 0;
            #pragma unroll
            for (int k = 0; k < ADJR; ++k) {
                if (k < nfix) {
                    uint32_t e = (w[k >> 1] >> ((k & 1) * 16)) & 0xFFFFu;
                    uint32_t d = e - base;
                    if (d < 64u) K |= (1ull << d);
                }
            }
            if (novf && inb) {
                for (int k = 0; k < novf; ++k) {
                    uint32_t e = ovfb[k];
                    if ((int)(e >> 16) == r) {
                        uint32_t d = (e & 0xFFFFu) - base;
                        if (d < 64u) K |= (1ull << d);
                    }
                }
            }
            int vbit = inb ? (int)((mask[r >> 5] >> (r & 31)) & 1u) : 0;
            uint64_t valid = (uint64_t)__ballot(vbit);
            uint32_t Klo = (uint32_t)K, Khi = (uint32_t)(K >> 32);
            uint64_t todo = valid & (uint64_t)__ballot(K != 0);
            while (todo) {
                int s = __ffsll((unsigned long long)todo) - 1;
                if ((valid >> s) & 1ull) {
                    uint32_t kl = (uint32_t)__builtin_amdgcn_readlane((int)Klo, s);
                    uint32_t kh = (uint32_t)__builtin_amdgcn_readlane((int)Khi, s);
                    valid &= ~(((uint64_t)kh << 32) | (uint64_t)kl);
                }
                todo &= (todo - 1);
                todo &= valid;
            }
            uint64_t acc = valid;
            int cnt2 = __popcll(acc);
            int myacc = (int)((acc >> ln) & 1ull);
            uint64_t ltm = (ln == 0) ? 0ull : (~0ull >> (64 - ln));
            int pos = nsel + __popcll(acc & ltm);
            bool eff = myacc && (pos < POST_NMS);
            if (eff) {
                keeps[pos] = r;
                #pragma unroll
                for (int k = 0; k < ADJR; ++k) {
                    if (k < nfix) {
                        uint32_t e = (w[k >> 1] >> ((k & 1) * 16)) & 0xFFFFu;
                        atomicAnd(&mask[e >> 5], ~(1u << (e & 31)));
                    }
                }
                if (novf) {
                    for (int k = 0; k < novf; ++k) {
                        uint32_t e = ovfb[k];
                        if ((int)(e >> 16) == r) {
                            uint32_t n2 = e & 0xFFFFu;
                            atomicAnd(&mask[n2 >> 5], ~(1u << (n2 & 31)));
                        }
                    }
                }
            }
            nsel += cnt2;
        }
        if (ln == 0) snsel = nsel;
    }
    __syncthreads();
    int n = min(snsel, POST_NMS);
    const float4* pb = props + (size_t)b * PRE_NMS;
    float* outb = out + (size_t)b * POST_NMS * 5;
    for (int r = t; r < POST_NMS; r += 256) {
        float* row = outb + (size_t)r * 5;
        if (r < n) {
            float4 p = pb[keeps[r]];
            row[0] = (float)b; row[1] = p.x; row[2] = p.y; row[3] = p.z; row[4] = p.w;
        } else {
            row[0] = (float)b; row[1] = 0.0f; row[2] = 0.0f; row[3] = 0.0f; row[4] = 0.0f;
        }
    }
}

extern "C" void kernel_launch(void* const* d_in, const int* in_sizes, int n_in,
                              void* d_out, int out_size, void* d_ws, size_t ws_size,
                              hipStream_t stream) {
    const float* scores  = (const float*)d_in[0];
    const float* deltas  = (const float*)d_in[1];
    const float* im_info = (const float*)d_in[2];
    const float* anchors = (const float*)d_in[3];
    float* out = (float*)d_out;

    uint8_t* w = (uint8_t*)d_ws;
    uint32_t* hist     = (uint32_t*)(w);                // 262,144
    uint32_t* cnt      = (uint32_t*)(w + 262144);       // 64
    uint32_t* ccnt     = (uint32_t*)(w + 262208);       // 64
    uint32_t* Bsel     = (uint32_t*)(w + 262272);       // 64
    uint32_t* segcur   = (uint32_t*)(w + 262336);       // 64
    uint32_t* ovfcnt   = (uint32_t*)(w + 262400);       // 64 -> 262,464
    uint64_t* selk     = (uint64_t*)(w + 262464);       // 1,536,000 -> 1,798,464
    uint64_t* candbuf  = (uint64_t*)(w + 1798464);      // 2,097,152 -> 3,895,616
    uint32_t* aidx     = (uint32_t*)(w + 3895616);      // 768,000   -> 4,663,616
    float*    props    = (float*)(w + 4663616);         // 3,072,000 -> 7,735,616
    uint32_t* binpack  = (uint32_t*)(w + 7735616);      // 1,398,144 -> 9,133,760
    uint16_t* binlist  = (uint16_t*)(w + 9133760);      // 3,145,728 -> 12,279,488
    uint32_t* deg      = (uint32_t*)(w + 12279488);     // 768,000   -> 13,047,488
    uint16_t* adjfix   = (uint16_t*)(w + 13047488);     // 4,608,000 -> 17,655,488
    uint32_t* ovf      = (uint32_t*)(w + 17655488);     // 262,144   -> 17,917,632

    hipLaunchKernelGGL(k_init, dim3(256), dim3(256), 0, stream,
                       hist, cnt, ccnt, ovfcnt, deg, segcur);
    hipLaunchKernelGGL(k_histv, dim3(32, NBATCH), dim3(256), 0, stream, scores, hist);
    hipLaunchKernelGGL(k_pickv, dim3(NBATCH), dim3(64), 0, stream, hist, Bsel);
    hipLaunchKernelGGL(k_splitv, dim3(128, NBATCH), dim3(256), 0, stream,
                       scores, Bsel, cnt, ccnt, selk, candbuf);
    hipLaunchKernelGGL(k_rankb, dim3(NBATCH), dim3(1024), 0, stream,
                       selk, candbuf, cnt, ccnt, aidx);
    hipLaunchKernelGGL(k_gather, dim3(47, NBATCH), dim3(256), 0, stream,
                       (const float4*)anchors, (const float4*)deltas, im_info, aidx,
                       (float4*)props);
    hipLaunchKernelGGL(k_binfuse8, dim3(NBATCH, 8), dim3(1024), 0, stream,
                       (const float4*)props, binpack, binlist, segcur);
    hipLaunchKernelGGL(k_search, dim3(188 * NBATCH), dim3(256), 0, stream,
                       (const float4*)props, binpack, binlist,
                       deg, adjfix, ovf, ovfcnt);
    hipLaunchKernelGGL(k_greedy, dim3(NBATCH), dim3(256), 0, stream,
                       deg, adjfix, ovf, ovfcnt, (const float4*)props, out);
}